// Round 1
// baseline (528.944 us; speedup 1.0000x reference)
//
#include <hip/hip_runtime.h>

#define NN 20000
#define DEG 16
#define HDIM 128
#define GDIM 512

typedef __attribute__((ext_vector_type(8))) short bf16x8;
typedef __attribute__((ext_vector_type(4))) float f32x4;

#define L2E  1.4426950408889634f
#define L2E2 2.8853900817779268f

__device__ __forceinline__ f32x4 mfma16(bf16x8 a, bf16x8 b, f32x4 c) {
    return __builtin_amdgcn_mfma_f32_16x16x32_bf16(a, b, c, 0, 0, 0);
}

__device__ __forceinline__ unsigned short f2bf(float f) {
    unsigned u = __builtin_bit_cast(unsigned, f);
    u += 0x7FFFu + ((u >> 16) & 1u);
    return (unsigned short)(u >> 16);
}

// ---------------- weight convert (f32 -> bf16, fold log2e into gate scales) --
struct CvtArgs {
    const float *wih, *whh, *wl, *wr;
    unsigned short *dih, *dhh, *dl, *dr;
};

__global__ __launch_bounds__(256) void cvt_kernel(CvtArgs a) {
    int b = blockIdx.x, t = threadIdx.x;
    if (b < 256) {                       // w_ih [512,128]
        int i = b * 256 + t;
        float s = ((i >> 14) == 2) ? L2E2 : L2E;   // gate g gets 2*log2e
        a.dih[i] = f2bf(a.wih[i] * s);
    } else if (b < 512) {                // w_hh [512,128]
        int i = (b - 256) * 256 + t;
        float s = ((i >> 14) == 2) ? L2E2 : L2E;
        a.dhh[i] = f2bf(a.whh[i] * s);
    } else if (b < 576) {                // w_l [128,128]
        int i = (b - 512) * 256 + t;
        a.dl[i] = f2bf(a.wl[i]);
    } else {                             // w_r [128,128]
        int i = (b - 576) * 256 + t;
        a.dr[i] = f2bf(a.wr[i]);
    }
}

// ---------------- h0 = concat(x, emb[type]) -> bf16 -------------------------
__global__ __launch_bounds__(256) void embed_kernel(
        const float* __restrict__ x, const int* __restrict__ types,
        const float* __restrict__ emb, unsigned short* __restrict__ h0) {
    int i = blockIdx.x * 256 + threadIdx.x;      // < NN*128
    int n = i >> 7, c = i & 127;
    float v = (c < 96) ? x[n * 96 + c] : emb[types[n] * 32 + (c - 96)];
    h0[i] = f2bf(v);
}

// ---------------- Xih = h @ w_ih^T + scale*(b_ih+b_hh)  [NN,512] f32 --------
__global__ __launch_bounds__(256) void gemmA_kernel(
        const unsigned short* __restrict__ h, const unsigned short* __restrict__ wih,
        const float* __restrict__ bih, const float* __restrict__ bhh,
        float* __restrict__ xih) {
    const int lane = threadIdx.x & 63, wv = threadIdx.x >> 6;
    const int cl = lane & 15, k8 = (lane >> 4) * 8;
    const int mbase = blockIdx.x * 16;

    bf16x8 a[4];
#pragma unroll
    for (int kt = 0; kt < 4; ++kt)
        a[kt] = *(const bf16x8*)(h + (mbase + cl) * HDIM + kt * 32 + k8);

    const int rb = mbase + (lane >> 4) * 4;
#pragma unroll
    for (int nt = 0; nt < 8; ++nt) {
        const int d = wv * 128 + nt * 16 + cl;
        f32x4 acc = {0.f, 0.f, 0.f, 0.f};
#pragma unroll
        for (int kt = 0; kt < 4; ++kt) {
            bf16x8 b = *(const bf16x8*)(wih + d * HDIM + kt * 32 + k8);
            acc = mfma16(a[kt], b, acc);
        }
        float s = ((d >> 7) == 2) ? L2E2 : L2E;
        float bias = (bih[d] + bhh[d]) * s;
#pragma unroll
        for (int r = 0; r < 4; ++r)
            xih[(size_t)(rb + r) * GDIM + d] = acc[r] + bias;
    }
}

// ---------------- fused per-node LSTM over 16 neighbors ---------------------
// block = 512 threads (8 waves), 32 nodes/block. Wave w owns gate-dims
// [16w,16w+16) of each of the 4 gates; w_hh fragments resident in VGPRs.
__global__ __launch_bounds__(512) void lstm_kernel(
        const float* __restrict__ xih, const unsigned short* __restrict__ whh,
        const int* __restrict__ esrc, unsigned short* __restrict__ agg) {
    __shared__ unsigned short hbuf[2][32][136];   // +8 pad: conflict-free b128
    __shared__ int srcs[512];

    const int tid = threadIdx.x;
    const int lane = tid & 63, wv = tid >> 6;
    const int cl = lane & 15, qh = lane >> 4, k8 = qh * 8;
    const int colb = wv * 16 + cl;
    const int base = blockIdx.x * 32;

    srcs[tid] = esrc[base * DEG + tid];
    __syncthreads();

    bf16x8 bfr[4][4];                              // [ktile][gate]
#pragma unroll
    for (int kt = 0; kt < 4; ++kt)
#pragma unroll
        for (int g = 0; g < 4; ++g)
            bfr[kt][g] = *(const bf16x8*)(whh + (g * 128 + colb) * HDIM + kt * 32 + k8);

    float c[2][4] = {};
    float hreg[2][4];
    float xv[2][4][4];

    // prefetch Xih gather for t=0
#pragma unroll
    for (int mt = 0; mt < 2; ++mt)
#pragma unroll
        for (int r = 0; r < 4; ++r) {
            int s = srcs[(mt * 16 + qh * 4 + r) * DEG + 0];
            const float* p = xih + (size_t)s * GDIM + colb;
#pragma unroll
            for (int g = 0; g < 4; ++g) xv[mt][g][r] = p[g * 128];
        }

    for (int t = 0; t < 16; ++t) {
        f32x4 acc[2][4];
#pragma unroll
        for (int mt = 0; mt < 2; ++mt)
#pragma unroll
            for (int g = 0; g < 4; ++g) {
                f32x4 v;
#pragma unroll
                for (int r = 0; r < 4; ++r) v[r] = xv[mt][g][r];
                acc[mt][g] = v;
            }
        // prefetch next step's gather (overlaps MFMA + nonlinearity)
        {
            int tn = (t + 1) & 15;
#pragma unroll
            for (int mt = 0; mt < 2; ++mt)
#pragma unroll
                for (int r = 0; r < 4; ++r) {
                    int s = srcs[(mt * 16 + qh * 4 + r) * DEG + tn];
                    const float* p = xih + (size_t)s * GDIM + colb;
#pragma unroll
                    for (int g = 0; g < 4; ++g) xv[mt][g][r] = p[g * 128];
                }
        }
        if (t > 0) {                                // h0 == 0: skip recurrent MFMA at t=0
            const int rb = (t + 1) & 1;
#pragma unroll
            for (int mt = 0; mt < 2; ++mt) {
                bf16x8 a[4];
#pragma unroll
                for (int kt = 0; kt < 4; ++kt)
                    a[kt] = *(const bf16x8*)(&hbuf[rb][mt * 16 + cl][kt * 32 + k8]);
#pragma unroll
                for (int g = 0; g < 4; ++g)
#pragma unroll
                    for (int kt = 0; kt < 4; ++kt)
                        acc[mt][g] = mfma16(a[kt], bfr[kt][g], acc[mt][g]);
            }
        }
        const int wb = t & 1;
#pragma unroll
        for (int mt = 0; mt < 2; ++mt)
#pragma unroll
            for (int r = 0; r < 4; ++r) {
                float gi = acc[mt][0][r], gf = acc[mt][1][r];
                float gg = acc[mt][2][r], go = acc[mt][3][r];
                // preactivations already scaled by log2e (2*log2e for g)
                float is = __builtin_amdgcn_rcpf(1.f + __builtin_amdgcn_exp2f(-gi));
                float fs = __builtin_amdgcn_rcpf(1.f + __builtin_amdgcn_exp2f(-gf));
                float gt = 1.f - 2.f * __builtin_amdgcn_rcpf(__builtin_amdgcn_exp2f(gg) + 1.f);
                float os = __builtin_amdgcn_rcpf(1.f + __builtin_amdgcn_exp2f(-go));
                float cc = fs * c[mt][r] + is * gt;
                c[mt][r] = cc;
                float th = 1.f - 2.f * __builtin_amdgcn_rcpf(__builtin_amdgcn_exp2f(cc * L2E2) + 1.f);
                float hv = os * th;
                hreg[mt][r] = hv;
                hbuf[wb][mt * 16 + qh * 4 + r][colb] = f2bf(hv);
            }
        __syncthreads();
    }

#pragma unroll
    for (int mt = 0; mt < 2; ++mt)
#pragma unroll
        for (int r = 0; r < 4; ++r)
            agg[(size_t)(base + mt * 16 + qh * 4 + r) * HDIM + colb] = f2bf(hreg[mt][r]);
}

// ---------------- out = agg@w_l^T + h@w_r^T + b_l (opt relu / f32 final) ----
__global__ __launch_bounds__(256) void gemmC_kernel(
        const unsigned short* __restrict__ agg, const unsigned short* __restrict__ hcur,
        const unsigned short* __restrict__ wl, const unsigned short* __restrict__ wr,
        const float* __restrict__ bl, unsigned short* __restrict__ hnext,
        float* __restrict__ fout, int relu) {
    const int lane = threadIdx.x & 63, wv = threadIdx.x >> 6;
    const int mtg = blockIdx.x * 4 + wv;
    if (mtg >= NN / 16) return;
    const int cl = lane & 15, k8 = (lane >> 4) * 8;
    const int mbase = mtg * 16;

    f32x4 acc[8];
#pragma unroll
    for (int nt = 0; nt < 8; ++nt) acc[nt] = (f32x4){0.f, 0.f, 0.f, 0.f};

#pragma unroll
    for (int kt = 0; kt < 8; ++kt) {
        const unsigned short* As = (kt < 4) ? agg : hcur;
        const unsigned short* Bs = (kt < 4) ? wl : wr;
        const int k0 = (kt & 3) * 32 + k8;
        bf16x8 a = *(const bf16x8*)(As + (size_t)(mbase + cl) * HDIM + k0);
#pragma unroll
        for (int nt = 0; nt < 8; ++nt) {
            bf16x8 b = *(const bf16x8*)(Bs + (nt * 16 + cl) * HDIM + k0);
            acc[nt] = mfma16(a, b, acc[nt]);
        }
    }
    const int rb = mbase + (lane >> 4) * 4;
#pragma unroll
    for (int nt = 0; nt < 8; ++nt) {
        const int d = nt * 16 + cl;
        float bias = bl[d];
#pragma unroll
        for (int r = 0; r < 4; ++r) {
            float v = acc[nt][r] + bias;
            if (relu) v = fmaxf(v, 0.f);
            if (fout) fout[(size_t)(rb + r) * HDIM + d] = v;
            else      hnext[(size_t)(rb + r) * HDIM + d] = f2bf(v);
        }
    }
}

// ---------------- host ------------------------------------------------------
extern "C" void kernel_launch(void* const* d_in, const int* in_sizes, int n_in,
                              void* d_out, int out_size, void* d_ws, size_t ws_size,
                              hipStream_t stream) {
    (void)in_sizes; (void)n_in; (void)out_size; (void)ws_size;

    const float* x     = (const float*)d_in[0];
    const int*   types = (const int*)d_in[1];
    const int*   esrc  = (const int*)d_in[2];
    const float* emb   = (const float*)d_in[4];

    char* ws = (char*)d_ws;
    unsigned short* hA  = (unsigned short*)ws; ws += (size_t)NN * HDIM * 2;
    unsigned short* hB  = (unsigned short*)ws; ws += (size_t)NN * HDIM * 2;
    unsigned short* agg = (unsigned short*)ws; ws += (size_t)NN * HDIM * 2;
    float*          xih = (float*)ws;          ws += (size_t)NN * GDIM * 4;
    unsigned short* wbf = (unsigned short*)ws; // 12 tensors, 163840 elems/layer

    unsigned short *wihb[3], *whhb[3], *wlb[3], *wrb[3];
    for (int l = 0; l < 3; ++l) {
        unsigned short* lb = wbf + (size_t)l * 163840;
        wihb[l] = lb;
        whhb[l] = lb + 65536;
        wlb[l]  = lb + 131072;
        wrb[l]  = lb + 147456;
        CvtArgs a;
        a.wih = (const float*)d_in[5 + 7 * l + 0];
        a.whh = (const float*)d_in[5 + 7 * l + 1];
        a.wl  = (const float*)d_in[5 + 7 * l + 4];
        a.wr  = (const float*)d_in[5 + 7 * l + 6];
        a.dih = wihb[l]; a.dhh = whhb[l]; a.dl = wlb[l]; a.dr = wrb[l];
        cvt_kernel<<<640, 256, 0, stream>>>(a);
    }

    embed_kernel<<<(NN * HDIM) / 256, 256, 0, stream>>>(x, types, emb, hA);

    unsigned short* hc = hA;
    unsigned short* hn = hB;
    for (int l = 0; l < 3; ++l) {
        const float* bih = (const float*)d_in[5 + 7 * l + 2];
        const float* bhh = (const float*)d_in[5 + 7 * l + 3];
        const float* bl  = (const float*)d_in[5 + 7 * l + 5];

        gemmA_kernel<<<NN / 16, 256, 0, stream>>>(hc, wihb[l], bih, bhh, xih);
        lstm_kernel<<<NN / 32, 512, 0, stream>>>(xih, whhb[l], esrc, agg);

        int final = (l == 2);
        gemmC_kernel<<<(NN / 16 + 3) / 4, 256, 0, stream>>>(
            agg, hc, wlb[l], wrb[l], bl,
            final ? nullptr : hn,
            final ? (float*)d_out : nullptr,
            final ? 0 : 1);
        unsigned short* t = hc; hc = hn; hn = t;
    }
}

// Round 2
// 369.940 us; speedup vs baseline: 1.4298x; 1.4298x over previous
//
#include <hip/hip_runtime.h>

#define NN 20000
#define DEG 16
#define HDIM 128
#define GDIM 512

typedef __attribute__((ext_vector_type(8))) short bf16x8;
typedef __attribute__((ext_vector_type(4))) float f32x4;

#define L2E  1.4426950408889634f
#define L2E2 2.8853900817779268f

__device__ __forceinline__ f32x4 mfma16(bf16x8 a, bf16x8 b, f32x4 c) {
    return __builtin_amdgcn_mfma_f32_16x16x32_bf16(a, b, c, 0, 0, 0);
}

__device__ __forceinline__ unsigned short f2bf(float f) {
    unsigned u = __builtin_bit_cast(unsigned, f);
    u += 0x7FFFu + ((u >> 16) & 1u);
    return (unsigned short)(u >> 16);
}

__device__ __forceinline__ float bfu2f(unsigned long long raw, int g) {
    unsigned u = (unsigned)(raw >> (g * 16)) & 0xFFFFu;
    return __builtin_bit_cast(float, u << 16);
}

// lgkmcnt-only barrier: lets gather prefetch (vmcnt) stay in flight across it
__device__ __forceinline__ void barrier_lgkm() {
    asm volatile("s_waitcnt lgkmcnt(0)\ns_barrier" ::: "memory");
}

// ---------------- weight convert (f32 -> bf16, fold log2e into gate scales) --
struct CvtArgs {
    const float *wih[3], *whh[3], *wl[3], *wr[3];
    unsigned short *dih[3], *dhh[3], *dl[3], *dr[3];
};

__global__ __launch_bounds__(256) void cvt_kernel(CvtArgs a) {
    int l = blockIdx.x / 640, b = blockIdx.x % 640, t = threadIdx.x;
    if (b < 256) {                       // w_ih [512,128]
        int i = b * 256 + t;
        float s = ((i >> 14) == 2) ? L2E2 : L2E;   // gate g gets 2*log2e
        a.dih[l][i] = f2bf(a.wih[l][i] * s);
    } else if (b < 512) {                // w_hh [512,128]
        int i = (b - 256) * 256 + t;
        float s = ((i >> 14) == 2) ? L2E2 : L2E;
        a.dhh[l][i] = f2bf(a.whh[l][i] * s);
    } else if (b < 576) {                // w_l [128,128]
        int i = (b - 512) * 256 + t;
        a.dl[l][i] = f2bf(a.wl[l][i]);
    } else {                             // w_r [128,128]
        int i = (b - 576) * 256 + t;
        a.dr[l][i] = f2bf(a.wr[l][i]);
    }
}

// ---------------- h0 = concat(x, emb[type]) -> bf16 -------------------------
__global__ __launch_bounds__(256) void embed_kernel(
        const float* __restrict__ x, const int* __restrict__ types,
        const float* __restrict__ emb, unsigned short* __restrict__ h0) {
    int i = blockIdx.x * 256 + threadIdx.x;      // < NN*128
    int n = i >> 7, c = i & 127;
    float v = (c < 96) ? x[n * 96 + c] : emb[types[n] * 32 + (c - 96)];
    h0[i] = f2bf(v);
}

// ---- Xih = h @ w_ih^T + scale*(b_ih+b_hh), bf16 packed [node][col][gate] ---
__global__ __launch_bounds__(256) void gemmA_kernel(
        const unsigned short* __restrict__ h, const unsigned short* __restrict__ wih,
        const float* __restrict__ bih, const float* __restrict__ bhh,
        unsigned short* __restrict__ xihb) {
    const int lane = threadIdx.x & 63, wv = threadIdx.x >> 6;   // wv = col block
    const int cl = lane & 15, qh = lane >> 4, k8 = qh * 8;
    const int mbase = blockIdx.x * 16;

    bf16x8 a[4];
#pragma unroll
    for (int kt = 0; kt < 4; ++kt)
        a[kt] = *(const bf16x8*)(h + (mbase + cl) * HDIM + kt * 32 + k8);

    f32x4 acc[2][4];
#pragma unroll
    for (int nt = 0; nt < 2; ++nt)
#pragma unroll
        for (int g = 0; g < 4; ++g) acc[nt][g] = (f32x4){0.f, 0.f, 0.f, 0.f};

#pragma unroll
    for (int nt = 0; nt < 2; ++nt) {
        const int col = wv * 32 + nt * 16 + cl;
#pragma unroll
        for (int g = 0; g < 4; ++g)
#pragma unroll
            for (int kt = 0; kt < 4; ++kt) {
                bf16x8 b = *(const bf16x8*)(wih + (g * 128 + col) * HDIM + kt * 32 + k8);
                acc[nt][g] = mfma16(a[kt], b, acc[nt][g]);
            }
    }

    const int rb = mbase + qh * 4;
#pragma unroll
    for (int nt = 0; nt < 2; ++nt) {
        const int col = wv * 32 + nt * 16 + cl;
        float bias[4];
#pragma unroll
        for (int g = 0; g < 4; ++g)
            bias[g] = (bih[g * 128 + col] + bhh[g * 128 + col]) * ((g == 2) ? L2E2 : L2E);
#pragma unroll
        for (int r = 0; r < 4; ++r) {
            unsigned long long pk = 0;
#pragma unroll
            for (int g = 0; g < 4; ++g)
                pk |= (unsigned long long)f2bf(acc[nt][g][r] + bias[g]) << (16 * g);
            *(unsigned long long*)(xihb + (size_t)(rb + r) * GDIM + col * 4) = pk;
        }
    }
}

// ---------------- fused per-node LSTM over 16 neighbors ---------------------
// 512 threads (8 waves), 16 nodes/block. Wave w owns gate-dims [16w,16w+16)
// of each of the 4 gates; w_hh fragments resident in VGPRs. Per edge-row each
// thread reads ONE b64 (4 gates packed bf16) from the xihb table.
__global__ __launch_bounds__(512, 4) void lstm_kernel(
        const unsigned short* __restrict__ xihb, const unsigned short* __restrict__ whh,
        const int* __restrict__ esrc, unsigned short* __restrict__ agg) {
    __shared__ unsigned short hbuf[2][16][136];   // +8 pad
    __shared__ int srcs[256];

    const int tid = threadIdx.x;
    const int lane = tid & 63, wv = tid >> 6;
    const int cl = lane & 15, qh = lane >> 4, k8 = qh * 8;
    const int colb = wv * 16 + cl;
    const int base = blockIdx.x * 16;

    if (tid < 256) srcs[tid] = esrc[base * DEG + tid];
    __syncthreads();

    bf16x8 bfr[4][4];                              // [ktile][gate]
#pragma unroll
    for (int kt = 0; kt < 4; ++kt)
#pragma unroll
        for (int g = 0; g < 4; ++g)
            bfr[kt][g] = *(const bf16x8*)(whh + (g * 128 + colb) * HDIM + kt * 32 + k8);

    float c[4] = {};
    float hreg[4];
    unsigned long long xr[4];

#pragma unroll
    for (int r = 0; r < 4; ++r) {
        int s = srcs[(qh * 4 + r) * DEG + 0];
        xr[r] = *(const unsigned long long*)(xihb + (size_t)s * GDIM + colb * 4);
    }

    for (int t = 0; t < 16; ++t) {
        f32x4 acc[4];
#pragma unroll
        for (int g = 0; g < 4; ++g)
#pragma unroll
            for (int r = 0; r < 4; ++r) acc[g][r] = bfu2f(xr[r], g);

        // prefetch next step's gather (in flight across barrier: lgkm-only)
        {
            int tn = (t + 1) & 15;
#pragma unroll
            for (int r = 0; r < 4; ++r) {
                int s = srcs[(qh * 4 + r) * DEG + tn];
                xr[r] = *(const unsigned long long*)(xihb + (size_t)s * GDIM + colb * 4);
            }
        }
        if (t > 0) {                                // h0 == 0: skip MFMA at t=0
            const int rb = (t + 1) & 1;
            bf16x8 a[4];
#pragma unroll
            for (int kt = 0; kt < 4; ++kt)
                a[kt] = *(const bf16x8*)(&hbuf[rb][cl][kt * 32 + k8]);
#pragma unroll
            for (int g = 0; g < 4; ++g)
#pragma unroll
                for (int kt = 0; kt < 4; ++kt)
                    acc[g] = mfma16(a[kt], bfr[kt][g], acc[g]);
        }
        const int wb = t & 1;
#pragma unroll
        for (int r = 0; r < 4; ++r) {
            float gi = acc[0][r], gf = acc[1][r];
            float gg = acc[2][r], go = acc[3][r];
            float is = __builtin_amdgcn_rcpf(1.f + __builtin_amdgcn_exp2f(-gi));
            float fs = __builtin_amdgcn_rcpf(1.f + __builtin_amdgcn_exp2f(-gf));
            float gt = 1.f - 2.f * __builtin_amdgcn_rcpf(__builtin_amdgcn_exp2f(gg) + 1.f);
            float os = __builtin_amdgcn_rcpf(1.f + __builtin_amdgcn_exp2f(-go));
            float cc = fs * c[r] + is * gt;
            c[r] = cc;
            float th = 1.f - 2.f * __builtin_amdgcn_rcpf(__builtin_amdgcn_exp2f(cc * L2E2) + 1.f);
            float hv = os * th;
            hreg[r] = hv;
            hbuf[wb][qh * 4 + r][colb] = f2bf(hv);
        }
        barrier_lgkm();
    }

#pragma unroll
    for (int r = 0; r < 4; ++r)
        agg[(size_t)(base + qh * 4 + r) * HDIM + colb] = f2bf(hreg[r]);
}

// ---------------- out = agg@w_l^T + h@w_r^T + b_l (opt relu / f32 final) ----
__global__ __launch_bounds__(256) void gemmC_kernel(
        const unsigned short* __restrict__ agg, const unsigned short* __restrict__ hcur,
        const unsigned short* __restrict__ wl, const unsigned short* __restrict__ wr,
        const float* __restrict__ bl, unsigned short* __restrict__ hnext,
        float* __restrict__ fout, int relu) {
    const int lane = threadIdx.x & 63, wv = threadIdx.x >> 6;
    const int mtg = blockIdx.x * 4 + wv;
    if (mtg >= NN / 16) return;
    const int cl = lane & 15, k8 = (lane >> 4) * 8;
    const int mbase = mtg * 16;

    f32x4 acc[8];
#pragma unroll
    for (int nt = 0; nt < 8; ++nt) acc[nt] = (f32x4){0.f, 0.f, 0.f, 0.f};

#pragma unroll
    for (int kt = 0; kt < 8; ++kt) {
        const unsigned short* As = (kt < 4) ? agg : hcur;
        const unsigned short* Bs = (kt < 4) ? wl : wr;
        const int k0 = (kt & 3) * 32 + k8;
        bf16x8 a = *(const bf16x8*)(As + (size_t)(mbase + cl) * HDIM + k0);
#pragma unroll
        for (int nt = 0; nt < 8; ++nt) {
            bf16x8 b = *(const bf16x8*)(Bs + (nt * 16 + cl) * HDIM + k0);
            acc[nt] = mfma16(a, b, acc[nt]);
        }
    }
    const int rb = mbase + (lane >> 4) * 4;
#pragma unroll
    for (int nt = 0; nt < 8; ++nt) {
        const int d = nt * 16 + cl;
        float bias = bl[d];
#pragma unroll
        for (int r = 0; r < 4; ++r) {
            float v = acc[nt][r] + bias;
            if (relu) v = fmaxf(v, 0.f);
            if (fout) fout[(size_t)(rb + r) * HDIM + d] = v;
            else      hnext[(size_t)(rb + r) * HDIM + d] = f2bf(v);
        }
    }
}

// ---------------- host ------------------------------------------------------
extern "C" void kernel_launch(void* const* d_in, const int* in_sizes, int n_in,
                              void* d_out, int out_size, void* d_ws, size_t ws_size,
                              hipStream_t stream) {
    (void)in_sizes; (void)n_in; (void)out_size; (void)ws_size;

    const float* x     = (const float*)d_in[0];
    const int*   types = (const int*)d_in[1];
    const int*   esrc  = (const int*)d_in[2];
    const float* emb   = (const float*)d_in[4];

    char* ws = (char*)d_ws;
    unsigned short* hA   = (unsigned short*)ws; ws += (size_t)NN * HDIM * 2;
    unsigned short* hB   = (unsigned short*)ws; ws += (size_t)NN * HDIM * 2;
    unsigned short* agg  = (unsigned short*)ws; ws += (size_t)NN * HDIM * 2;
    unsigned short* xihb = (unsigned short*)ws; ws += (size_t)NN * GDIM * 2;
    unsigned short* wbf  = (unsigned short*)ws; // 12 tensors, 163840 elems/layer

    unsigned short *wihb[3], *whhb[3], *wlb[3], *wrb[3];
    CvtArgs ca;
    for (int l = 0; l < 3; ++l) {
        unsigned short* lb = wbf + (size_t)l * 163840;
        wihb[l] = lb;
        whhb[l] = lb + 65536;
        wlb[l]  = lb + 131072;
        wrb[l]  = lb + 147456;
        ca.wih[l] = (const float*)d_in[5 + 7 * l + 0];
        ca.whh[l] = (const float*)d_in[5 + 7 * l + 1];
        ca.wl[l]  = (const float*)d_in[5 + 7 * l + 4];
        ca.wr[l]  = (const float*)d_in[5 + 7 * l + 6];
        ca.dih[l] = wihb[l]; ca.dhh[l] = whhb[l]; ca.dl[l] = wlb[l]; ca.dr[l] = wrb[l];
    }
    cvt_kernel<<<1920, 256, 0, stream>>>(ca);

    embed_kernel<<<(NN * HDIM) / 256, 256, 0, stream>>>(x, types, emb, hA);

    unsigned short* hc = hA;
    unsigned short* hn = hB;
    for (int l = 0; l < 3; ++l) {
        const float* bih = (const float*)d_in[5 + 7 * l + 2];
        const float* bhh = (const float*)d_in[5 + 7 * l + 3];
        const float* bl  = (const float*)d_in[5 + 7 * l + 5];

        gemmA_kernel<<<NN / 16, 256, 0, stream>>>(hc, wihb[l], bih, bhh, xihb);
        lstm_kernel<<<NN / 16, 512, 0, stream>>>(xihb, whhb[l], esrc, agg);

        int final = (l == 2);
        gemmC_kernel<<<(NN / 16 + 3) / 4, 256, 0, stream>>>(
            agg, hc, wlb[l], wrb[l], bl,
            final ? nullptr : hn,
            final ? (float*)d_out : nullptr,
            final ? 0 : 1);
        unsigned short* t = hc; hc = hn; hn = t;
    }
}